// Round 20
// baseline (121.135 us; speedup 1.0000x reference)
//
#include <hip/hip_runtime.h>
#include <hip/hip_bf16.h>
#include <math.h>

// Problem constants
#define BB 2
#define NN 2048
#define CC 768
#define NHEAD 12
#define HD 64
#define C3 2304
#define NSP 2    // split-K factor
#define KVB 128  // keys per tile (halves barrier count vs 64)

typedef __attribute__((ext_vector_type(8))) _Float16 half8;
typedef __attribute__((ext_vector_type(4))) _Float16 half4;
typedef __attribute__((ext_vector_type(8))) short short8;
typedef __attribute__((ext_vector_type(4))) float f32x4;
typedef __attribute__((ext_vector_type(2))) unsigned uint2v;
#define MFMAH(a, b, c) __builtin_amdgcn_mfma_f32_16x16x32_f16(a, b, c, 0, 0, 0)
#define MFMAH16(a, b, c) __builtin_amdgcn_mfma_f32_16x16x16f16(a, b, c, 0, 0, 0)

__device__ __forceinline__ float fast_exp2(float x) {
  return __builtin_amdgcn_exp2f(x);  // v_exp_f32 (natively 2^x)
}
__device__ __forceinline__ ushort f2h(float x) {
  _Float16 h = (_Float16)x;  // v_cvt_f16_f32, RTN
  return __builtin_bit_cast(ushort, h);
}
__device__ __forceinline__ float h2f(ushort u) {
  return (float)__builtin_bit_cast(_Float16, u);  // v_cvt_f32_f16
}
__device__ __forceinline__ unsigned pk2h(float a, float b) {
  return __builtin_bit_cast(unsigned, __builtin_amdgcn_cvt_pkrtz(a, b));
}
__device__ __forceinline__ void gload_lds16(const void* gsrc, void* lds) {
  __builtin_amdgcn_global_load_lds(
      (const __attribute__((address_space(1))) unsigned int*)gsrc,
      (__attribute__((address_space(3))) unsigned int*)lds, 16, 0, 0);
}
__device__ __forceinline__ half8 ld_h8(const ushort* p) {
  return __builtin_bit_cast(half8, *reinterpret_cast<const short8*>(p));
}
__device__ __forceinline__ half4 ld_h4(const ushort* p) {
  return __builtin_bit_cast(half4, *reinterpret_cast<const uint2v*>(p));
}

// ---------------- fp32 -> f16 convert (rows) ----------------
__global__ __launch_bounds__(256) void conv_rows_kernel(const float* __restrict__ X,
                                                        ushort* __restrict__ Xf) {
  int idx = blockIdx.x * 256 + threadIdx.x;  // each converts 8 elems
  const float4 v0 = *reinterpret_cast<const float4*>(&X[(size_t)idx * 8]);
  const float4 v1 = *reinterpret_cast<const float4*>(&X[(size_t)idx * 8 + 4]);
  ushort h[8] = {f2h(v0.x), f2h(v0.y), f2h(v0.z), f2h(v0.w),
                 f2h(v1.x), f2h(v1.y), f2h(v1.z), f2h(v1.w)};
  *reinterpret_cast<uint4*>(&Xf[(size_t)idx * 8]) = *reinterpret_cast<uint4*>(h);
}

// ---------------- W [768][N] fp32 -> Wf [N][768] f16 ----------------
__global__ __launch_bounds__(256) void conv_transpose_kernel(const float* __restrict__ W,
                                                             ushort* __restrict__ Wf,
                                                             int N) {
  __shared__ float t[32][33];
  const int tx = threadIdx.x & 31, ty = threadIdx.x >> 5;  // 32 x 8
  const int n0 = blockIdx.x * 32, k0 = blockIdx.y * 32;
#pragma unroll
  for (int r = 0; r < 4; r++) {
    int kk = ty + r * 8;
    t[kk][tx] = W[(size_t)(k0 + kk) * N + n0 + tx];
  }
  __syncthreads();
#pragma unroll
  for (int r = 0; r < 4; r++) {
    int nn = ty + r * 8;
    Wf[(size_t)(n0 + nn) * CC + k0 + tx] = f2h(t[tx][nn]);
  }
}

// ---------------- f16 MFMA GEMM: C = A @ B^T, BK=64, BN=96 ----------------
template <int BM, bool F16OUT>
__global__ __launch_bounds__(256) void gemm_f16_kernel(const ushort* __restrict__ A,
                                                       const ushort* __restrict__ B,
                                                       void* __restrict__ Cout, int Nn) {
  constexpr int WM = BM / 2;   // 64 or 32
  constexpr int MR = WM / 16;  // 4 or 2
  constexpr int NR = 3;        // 48/16
  __shared__ __align__(16) ushort Asm[BM * 64];
  __shared__ __align__(16) ushort Bsm[96 * 64];
  const int tid = threadIdx.x;
  const int lane = tid & 63, w = tid >> 6;
  const int l15 = lane & 15, lg = lane >> 4;
  const int wr = w >> 1, wc = w & 1;
  const int m0 = blockIdx.y * BM, n0 = blockIdx.x * 96;
  const int srow = lane >> 3, lc = lane & 7;
  const int scp = lc ^ (srow & 7);  // pre-swizzled logical chunk

  f32x4 acc[MR][NR];
#pragma unroll
  for (int m = 0; m < MR; m++)
#pragma unroll
    for (int n = 0; n < NR; n++) acc[m][n] = (f32x4){0.f, 0.f, 0.f, 0.f};

  for (int k0 = 0; k0 < 768; k0 += 64) {
#pragma unroll
    for (int it = 0; it < BM / 32; it++) {
      int r0 = it * 32 + w * 8;
      int row = r0 + srow;
      gload_lds16(A + (size_t)(m0 + row) * CC + k0 + scp * 8, &Asm[r0 * 64]);
    }
#pragma unroll
    for (int it = 0; it < 3; it++) {
      int r0 = it * 32 + w * 8;
      int row = r0 + srow;
      gload_lds16(B + (size_t)(n0 + row) * CC + k0 + scp * 8, &Bsm[r0 * 64]);
    }
    __syncthreads();

    half8 ah[MR][2], bh[NR][2];
#pragma unroll
    for (int m = 0; m < MR; m++) {
      int row = wr * WM + m * 16 + l15;
#pragma unroll
      for (int s = 0; s < 2; s++)
        ah[m][s] = ld_h8(&Asm[row * 64 + ((s * 4 + lg) ^ (row & 7)) * 8]);
    }
#pragma unroll
    for (int n = 0; n < NR; n++) {
      int col = wc * 48 + n * 16 + l15;
#pragma unroll
      for (int s = 0; s < 2; s++)
        bh[n][s] = ld_h8(&Bsm[col * 64 + ((s * 4 + lg) ^ (col & 7)) * 8]);
    }
#pragma unroll
    for (int s = 0; s < 2; s++)
#pragma unroll
      for (int m = 0; m < MR; m++)
#pragma unroll
        for (int n = 0; n < NR; n++)
          acc[m][n] = MFMAH(ah[m][s], bh[n][s], acc[m][n]);
    __syncthreads();
  }

#pragma unroll
  for (int m = 0; m < MR; m++)
#pragma unroll
    for (int j = 0; j < 4; j++) {
      int row = m0 + wr * WM + m * 16 + lg * 4 + j;
#pragma unroll
      for (int n = 0; n < NR; n++) {
        int col = n0 + wc * 48 + n * 16 + l15;
        if constexpr (F16OUT) {
          ((ushort*)Cout)[(size_t)row * Nn + col] = f2h(acc[m][n][j]);
        } else {
          ((float*)Cout)[(size_t)row * Nn + col] = acc[m][n][j];
        }
      }
    }
}

// ---------------- RoPE (Q/K) from f16 qkv -> f16, Q pre-scaled ----------------
__global__ __launch_bounds__(256) void rope_f16_kernel(
    const ushort* __restrict__ qkvh, const float* __restrict__ cos_t,
    const float* __restrict__ sin_t, const float* __restrict__ cos_h,
    const float* __restrict__ sin_h, const float* __restrict__ cos_w,
    const float* __restrict__ sin_w, const int* __restrict__ t_idx,
    const int* __restrict__ h_idx, const int* __restrict__ w_idx,
    ushort* __restrict__ Qf, ushort* __restrict__ Kf) {
  const int tok = blockIdx.x;  // 0..B*N-1
  const int b = tok >> 11, n = tok & 2047;
  const int ti = t_idx[n], hi = h_idx[n], wi = w_idx[n];
  const ushort* base = qkvh + (size_t)tok * C3;
  const float QSC = 0.125f * 1.44269504088896f;

#pragma unroll
  for (int s = 0; s < 3; s++) {
    int j = threadIdx.x + s * 256;
    float c, sn, sign;
    int pj;
    if (j < 192) {
      int jj = j;
      c = cos_t[ti * 192 + jj];
      sn = sin_t[ti * 192 + jj];
      pj = (jj < 96) ? j + 96 : j - 96;
      sign = (jj < 96) ? -1.f : 1.f;
    } else if (j < 480) {
      int jj = j - 192;
      c = cos_h[hi * 288 + jj];
      sn = sin_h[hi * 288 + jj];
      pj = (jj < 144) ? j + 144 : j - 144;
      sign = (jj < 144) ? -1.f : 1.f;
    } else {
      int jj = j - 480;
      c = cos_w[wi * 288 + jj];
      sn = sin_w[wi * 288 + jj];
      pj = (jj < 144) ? j + 144 : j - 144;
      sign = (jj < 144) ? -1.f : 1.f;
    }
    float qv = h2f(base[j]), kv = h2f(base[768 + j]);
    float qp = h2f(base[pj]) * sign, kp = h2f(base[768 + pj]) * sign;
    float qr = fmaf(qv, c, qp * sn) * QSC;
    float kr = fmaf(kv, c, kp * sn);
    int h = j >> 6, d = j & 63;
    int bh = b * NHEAD + h;
    size_t o = ((size_t)bh * NN + n) * HD + d;
    Qf[o] = f2h(qr);
    Kf[o] = f2h(kr);
  }
}

// ---------------- V transpose: f16 qkv V-slice -> Vt [bh][d][n] f16 ----------------
__global__ __launch_bounds__(256) void v_transpose_kernel(const ushort* __restrict__ qkvh,
                                                          ushort* __restrict__ Vt) {
  __shared__ ushort t[64][70];
  const int bh = blockIdx.y;  // 0..23
  const int n0 = blockIdx.x * 64;
  const int b = bh / NHEAD, h = bh % NHEAD;
  const int row = threadIdx.x >> 2;       // token-local 0..63
  const int c0 = (threadIdx.x & 3) * 16;  // d-chunk
  const ushort* src = qkvh + (size_t)(b * NN + n0 + row) * C3 + 1536 + h * 64 + c0;
  ushort tmp16[16];
  *reinterpret_cast<uint4*>(tmp16) = *reinterpret_cast<const uint4*>(src);
  *reinterpret_cast<uint4*>(tmp16 + 8) = *reinterpret_cast<const uint4*>(src + 8);
#pragma unroll
  for (int i = 0; i < 16; i++) t[row][c0 + i] = tmp16[i];
  __syncthreads();
  const int d = threadIdx.x >> 2;
  const int tk0 = (threadIdx.x & 3) * 16;
  ushort tmp[16];
#pragma unroll
  for (int i = 0; i < 16; i++) tmp[i] = t[tk0 + i][d];
  ushort* dst = Vt + ((size_t)bh * HD + d) * NN + n0 + tk0;
  *reinterpret_cast<uint4*>(dst) = *reinterpret_cast<uint4*>(tmp);
  *reinterpret_cast<uint4*>(dst + 8) = *reinterpret_cast<uint4*>(tmp + 8);
}

// ---------------- f16 MFMA flash attention, QBLK=64, KVB=128, split-K=2 ----------
// Halved barrier count (8 tiles x 2 vs 16 x 2). K single-buffer 16KB +
// V double-buffer 32KB = 48KB -> 3 blocks/CU. PV via 16x16x16 (no butterfly).
__global__ __launch_bounds__(256, 3) void attn_mfma_kernel(
    const ushort* __restrict__ Qf, const ushort* __restrict__ Kf,
    const ushort* __restrict__ Vt, float* __restrict__ PartO,
    float* __restrict__ Partml) {
  __shared__ __align__(16) ushort smemK[KVB * 64];      // 16KB, [k][d]
  __shared__ __align__(16) ushort smemV[2][64 * KVB];   // 2x16KB, [d][k]
  const int tid = threadIdx.x;
  const int lane = tid & 63, w = tid >> 6;
  const int l15 = lane & 15, lg = lane >> 4;
  const int qt = blockIdx.x;  // 0..31 (64 q-rows each)
  const int bh = blockIdx.y;  // 0..23
  const int sp = blockIdx.z;  // 0..1 (k-range split)
  const size_t kbase = (size_t)bh * NN * HD;  // Qf/Kf token-major
  const size_t vbase = (size_t)bh * HD * NN;  // Vt d-major

  half8 qf[2];
  {
    const int r = qt * 64 + w * 16 + l15;
#pragma unroll
    for (int s = 0; s < 2; s++)
      qf[s] = ld_h8(Qf + kbase + (size_t)r * HD + s * 32 + lg * 8);
  }

  // staging lane decomposition (K rows 128B, V rows 256B)
  const int krow = lane >> 3, kc = lane & 7;
  const int vrow = lane >> 4, vc = lane & 15;

#define STAGE_K(kt_)                                                           \
  {                                                                            \
    _Pragma("unroll") for (int it = 0; it < 4; it++) {                         \
      int r0 = it * 32 + w * 8;                                                \
      int r = r0 + krow;                                                       \
      int cp = kc ^ (r & 7);                                                   \
      gload_lds16(Kf + kbase + (size_t)((kt_)*KVB + r) * 64 + cp * 8,          \
                  &smemK[r0 * 64]);                                            \
    }                                                                          \
  }
#define STAGE_V(kt_, vb_)                                                      \
  {                                                                            \
    _Pragma("unroll") for (int it = 0; it < 4; it++) {                         \
      int r0 = it * 16 + w * 4;                                                \
      int r = r0 + vrow;                                                       \
      int cp = vc ^ (r & 7);                                                   \
      gload_lds16(Vt + vbase + (size_t)r * NN + (kt_)*KVB + cp * 8,            \
                  &smemV[vb_][r0 * KVB]);                                      \
    }                                                                          \
  }

  f32x4 o_acc[4];
#pragma unroll
  for (int g = 0; g < 4; g++) o_acc[g] = (f32x4){0.f, 0.f, 0.f, 0.f};
  float m_run = -INFINITY, l_run = 0.f;  // per-lane partials

  const int rmask7 = l15 & 7;
  const int kt0 = sp * (16 / NSP), ktend = kt0 + (16 / NSP);  // 128-wide tiles

  STAGE_V(kt0, 0);
  STAGE_K(kt0);

  for (int kt = kt0; kt < ktend; kt++) {
    const int cur = (kt - kt0) & 1;
    __syncthreads();  // barA: K(kt), V(kt,cur) visible; V[cur^1] free of reads
    if (kt + 1 < ktend) STAGE_V(kt + 1, cur ^ 1);  // lands under this tile

    // ---- S^T = K Q^T (f16, 16x16x32), 128 k-rows ----
    f32x4 s_acc[8];
#pragma unroll
    for (int g = 0; g < 8; g++) s_acc[g] = (f32x4){0.f, 0.f, 0.f, 0.f};
    __builtin_amdgcn_s_setprio(1);
#pragma unroll
    for (int g = 0; g < 8; g++) {
      const int r = g * 16 + l15;
#pragma unroll
      for (int s = 0; s < 2; s++) {
        half8 ka = ld_h8(&smemK[r * 64 + ((s * 4 + lg) ^ (r & 7)) * 8]);
        s_acc[g] = MFMAH(ka, qf[s], s_acc[g]);
      }
    }
    __builtin_amdgcn_s_setprio(0);

    __syncthreads();                      // barB: all waves done reading K(kt)
    if (kt + 1 < ktend) STAGE_K(kt + 1);  // lands under softmax+PV

    // ---- softmax (exp2 domain), defer-max THR=8 ----
    float mg[8];
#pragma unroll
    for (int g = 0; g < 8; g++)
      mg[g] = fmaxf(fmaxf(s_acc[g][0], s_acc[g][1]), fmaxf(s_acc[g][2], s_acc[g][3]));
    float pm = fmaxf(fmaxf(fmaxf(mg[0], mg[1]), fmaxf(mg[2], mg[3])),
                     fmaxf(fmaxf(mg[4], mg[5]), fmaxf(mg[6], mg[7])));
    pm = fmaxf(pm, __shfl_xor(pm, 16, 64));
    pm = fmaxf(pm, __shfl_xor(pm, 32, 64));
    if (!__all(pm - m_run <= 8.0f)) {
      const float mn = fmaxf(m_run, pm);
      const float corr = fast_exp2(m_run - mn);
      m_run = mn;
      l_run *= corr;
#pragma unroll
      for (int g = 0; g < 4; g++)
#pragma unroll
        for (int j = 0; j < 4; j++) o_acc[g][j] *= corr;
    }
    float p[8][4];
#pragma unroll
    for (int g = 0; g < 8; g++)
#pragma unroll
      for (int j = 0; j < 4; j++) {
        p[g][j] = fast_exp2(s_acc[g][j] - m_run);
        l_run += p[g][j];
      }

    // ---- PV via 16x16x16: B-frag = p[kb][0..3] directly (no butterfly) ----
    __builtin_amdgcn_s_setprio(1);
#pragma unroll
    for (int kb = 0; kb < 8; kb++) {
      uint2v pw = {pk2h(p[kb][0], p[kb][1]), pk2h(p[kb][2], p[kb][3])};
      half4 pbh = __builtin_bit_cast(half4, pw);
      const int c = kb * 2 + (lg >> 1);  // 0..15
      const int off = ((c ^ rmask7) * 8 + (lg & 1) * 4);
#pragma unroll
      for (int g = 0; g < 4; g++) {
        half4 va = ld_h4(&smemV[cur][(g * 16 + l15) * KVB + off]);
        o_acc[g] = MFMAH16(va, pbh, o_acc[g]);
      }
    }
    __builtin_amdgcn_s_setprio(0);
  }

  // ---- epilogue: reduce l across the 4 q-column lanes, write partials ----
  l_run += __shfl_xor(l_run, 16, 64);
  l_run += __shfl_xor(l_run, 32, 64);
  const int q = qt * 64 + w * 16 + l15;
  const size_t pidx = ((size_t)(sp * 24 + bh) * NN + q);
#pragma unroll
  for (int g = 0; g < 4; g++) {
    *reinterpret_cast<float4*>(&PartO[pidx * 64 + g * 16 + lg * 4]) =
        make_float4(o_acc[g][0], o_acc[g][1], o_acc[g][2], o_acc[g][3]);
  }
  if (lg == 0) {
    Partml[pidx * 2] = m_run;
    Partml[pidx * 2 + 1] = l_run;
  }
#undef STAGE_K
#undef STAGE_V
}

// ---------------- split-K combine: merge NSP partials -> attnf f16 ----------------
__global__ __launch_bounds__(256) void attn_combine_kernel(
    const float* __restrict__ PartO, const float* __restrict__ Partml,
    ushort* __restrict__ Attnf) {
  const int qt = blockIdx.x;  // 0..31
  const int bh = blockIdx.y;  // 0..23
  const int b = bh / NHEAD, h = bh % NHEAD;
  const int tid = threadIdx.x;
  const int q = qt * 64 + (tid >> 2);
  const int d0 = (tid & 3) * 16;

  size_t idx[NSP];
  float mv[NSP], lv[NSP];
  float m = -INFINITY;
#pragma unroll
  for (int s = 0; s < NSP; s++) {
    idx[s] = ((size_t)(s * 24 + bh) * NN + q);
    mv[s] = Partml[idx[s] * 2];
    lv[s] = Partml[idx[s] * 2 + 1];
    m = fmaxf(m, mv[s]);
  }
  float wsum = 0.f, wgt[NSP];
#pragma unroll
  for (int s = 0; s < NSP; s++) {
    wgt[s] = fast_exp2(mv[s] - m);
    wsum += lv[s] * wgt[s];
  }
  const float inv = 1.0f / wsum;

  ushort hv[16];
#pragma unroll
  for (int d = 0; d < 16; d += 4) {
    float acc[4] = {0.f, 0.f, 0.f, 0.f};
#pragma unroll
    for (int s = 0; s < NSP; s++) {
      float4 a = *reinterpret_cast<const float4*>(&PartO[idx[s] * 64 + d0 + d]);
      acc[0] = fmaf(a.x, wgt[s], acc[0]);
      acc[1] = fmaf(a.y, wgt[s], acc[1]);
      acc[2] = fmaf(a.z, wgt[s], acc[2]);
      acc[3] = fmaf(a.w, wgt[s], acc[3]);
    }
#pragma unroll
    for (int i = 0; i < 4; i++) hv[d + i] = f2h(acc[i] * inv);
  }
  ushort* dst = Attnf + (size_t)(b * NN + q) * CC + h * 64 + d0;
  *reinterpret_cast<uint4*>(dst) = *reinterpret_cast<uint4*>(hv);
  *reinterpret_cast<uint4*>(dst + 8) = *reinterpret_cast<uint4*>(hv + 8);
}

// ---------------- launch ----------------
extern "C" void kernel_launch(void* const* d_in, const int* in_sizes, int n_in,
                              void* d_out, int out_size, void* d_ws, size_t ws_size,
                              hipStream_t stream) {
  const float* x = (const float*)d_in[0];
  const float* Wqkv = (const float*)d_in[1];
  const float* Wout = (const float*)d_in[2];
  const float* cos_t = (const float*)d_in[3];
  const float* sin_t = (const float*)d_in[4];
  const float* cos_h = (const float*)d_in[5];
  const float* sin_h = (const float*)d_in[6];
  const float* cos_w = (const float*)d_in[7];
  const float* sin_w = (const float*)d_in[8];
  const int* t_idx = (const int*)d_in[9];
  const int* h_idx = (const int*)d_in[10];
  const int* w_idx = (const int*)d_in[11];
  float* out = (float*)d_out;

  // region0: aliased by qkvh (f16 4096x2304, live gemm->rope/vtrans) and
  // PartO (NSP*24*2048*64 f32 = 6.29M floats, live attn->combine). Disjoint.
  const size_t R0 = (size_t)4096 * 2304;  // floats
  float* ws = (float*)d_ws;
  ushort* qkvh = (ushort*)ws;
  float* PartO = ws;
  ushort* us = (ushort*)(ws + R0);
  const size_t HS = (size_t)24 * 2048 * 64;  // 3.14M
  ushort* Qf = us;
  ushort* Kf = Qf + HS;
  ushort* Vt = Kf + HS;
  ushort* xf = Vt + HS;                     // 4096*768
  ushort* wqf = xf + (size_t)4096 * 768;    // 2304*768
  ushort* wof = wqf + (size_t)2304 * 768;   // 768*768
  ushort* attnf = wof + (size_t)768 * 768;  // 4096*768
  float* Partml = (float*)(attnf + (size_t)4096 * 768);  // NSP*24*2048*2 fp32

  // input conversions (f16)
  conv_rows_kernel<<<dim3(4096 * 768 / 8 / 256), 256, 0, stream>>>(x, xf);
  conv_transpose_kernel<<<dim3(C3 / 32, CC / 32), 256, 0, stream>>>(Wqkv, wqf, C3);
  conv_transpose_kernel<<<dim3(CC / 32, CC / 32), 256, 0, stream>>>(Wout, wof, CC);
  // qkv = x @ Wqkv  (f16 MFMA, f16 output)
  gemm_f16_kernel<128, true><<<dim3(C3 / 96, 4096 / 128), 256, 0, stream>>>(xf, wqf,
                                                                            qkvh, C3);
  // RoPE Q/K (f16 in/out) + V transpose (f16)
  rope_f16_kernel<<<dim3(BB * NN), 256, 0, stream>>>(qkvh, cos_t, sin_t, cos_h, sin_h,
                                                     cos_w, sin_w, t_idx, h_idx, w_idx,
                                                     Qf, Kf);
  v_transpose_kernel<<<dim3(NN / 64, BB * NHEAD), 256, 0, stream>>>(qkvh, Vt);
  // flash attention (f16 MFMA, QBLK=64, KVB=128, split-K=2)
  attn_mfma_kernel<<<dim3(NN / 64, BB * NHEAD, NSP), 256, 0, stream>>>(Qf, Kf, Vt,
                                                                       PartO, Partml);
  // combine partials -> f16 attnf
  attn_combine_kernel<<<dim3(NN / 64, BB * NHEAD), 256, 0, stream>>>(PartO, Partml,
                                                                     attnf);
  // out = attn @ Wout  (f16 MFMA, fp32 output)
  gemm_f16_kernel<64, false><<<dim3(CC / 96, 4096 / 64), 256, 0, stream>>>(attnf, wof,
                                                                           out, CC);
}

// Round 21
// 114.898 us; speedup vs baseline: 1.0543x; 1.0543x over previous
//
#include <hip/hip_runtime.h>
#include <hip/hip_bf16.h>
#include <math.h>

// Problem constants
#define BB 2
#define NN 2048
#define CC 768
#define NHEAD 12
#define HD 64
#define C3 2304
#define NSP 2  // split-K factor

typedef __attribute__((ext_vector_type(8))) _Float16 half8;
typedef __attribute__((ext_vector_type(4))) _Float16 half4;
typedef __attribute__((ext_vector_type(8))) short short8;
typedef __attribute__((ext_vector_type(4))) float f32x4;
typedef __attribute__((ext_vector_type(2))) unsigned uint2v;
#define MFMAH(a, b, c) __builtin_amdgcn_mfma_f32_16x16x32_f16(a, b, c, 0, 0, 0)
#define MFMAH16(a, b, c) __builtin_amdgcn_mfma_f32_16x16x16f16(a, b, c, 0, 0, 0)

__device__ __forceinline__ float fast_exp2(float x) {
  return __builtin_amdgcn_exp2f(x);  // v_exp_f32 (natively 2^x)
}
__device__ __forceinline__ ushort f2h(float x) {
  _Float16 h = (_Float16)x;  // v_cvt_f16_f32, RTN
  return __builtin_bit_cast(ushort, h);
}
__device__ __forceinline__ float h2f(ushort u) {
  return (float)__builtin_bit_cast(_Float16, u);  // v_cvt_f32_f16
}
__device__ __forceinline__ unsigned pk2h(float a, float b) {
  return __builtin_bit_cast(unsigned, __builtin_amdgcn_cvt_pkrtz(a, b));
}
__device__ __forceinline__ void gload_lds16(const void* gsrc, void* lds) {
  __builtin_amdgcn_global_load_lds(
      (const __attribute__((address_space(1))) unsigned int*)gsrc,
      (__attribute__((address_space(3))) unsigned int*)lds, 16, 0, 0);
}
__device__ __forceinline__ half8 ld_h8(const ushort* p) {
  return __builtin_bit_cast(half8, *reinterpret_cast<const short8*>(p));
}
__device__ __forceinline__ half4 ld_h4(const ushort* p) {
  return __builtin_bit_cast(half4, *reinterpret_cast<const uint2v*>(p));
}

// ---------------- fp32 -> f16 convert (rows) ----------------
__global__ __launch_bounds__(256) void conv_rows_kernel(const float* __restrict__ X,
                                                        ushort* __restrict__ Xf) {
  int idx = blockIdx.x * 256 + threadIdx.x;  // each converts 8 elems
  const float4 v0 = *reinterpret_cast<const float4*>(&X[(size_t)idx * 8]);
  const float4 v1 = *reinterpret_cast<const float4*>(&X[(size_t)idx * 8 + 4]);
  ushort h[8] = {f2h(v0.x), f2h(v0.y), f2h(v0.z), f2h(v0.w),
                 f2h(v1.x), f2h(v1.y), f2h(v1.z), f2h(v1.w)};
  *reinterpret_cast<uint4*>(&Xf[(size_t)idx * 8]) = *reinterpret_cast<uint4*>(h);
}

// ---------------- W [768][N] fp32 -> Wf [N][768] f16 ----------------
__global__ __launch_bounds__(256) void conv_transpose_kernel(const float* __restrict__ W,
                                                             ushort* __restrict__ Wf,
                                                             int N) {
  __shared__ float t[32][33];
  const int tx = threadIdx.x & 31, ty = threadIdx.x >> 5;  // 32 x 8
  const int n0 = blockIdx.x * 32, k0 = blockIdx.y * 32;
#pragma unroll
  for (int r = 0; r < 4; r++) {
    int kk = ty + r * 8;
    t[kk][tx] = W[(size_t)(k0 + kk) * N + n0 + tx];
  }
  __syncthreads();
#pragma unroll
  for (int r = 0; r < 4; r++) {
    int nn = ty + r * 8;
    Wf[(size_t)(n0 + nn) * CC + k0 + tx] = f2h(t[tx][nn]);
  }
}

// ---------------- f16 MFMA GEMM: C = A @ B^T, BK=64, BN=96 ----------------
// VOUT: columns >=1536 are the V projection; write them DIRECTLY transposed
// into Vt [bh][d][n] f16 (acc f32x4 over j = 4 consecutive tokens = contiguous
// n quad -> one 8B packed write). Other columns -> qkvh f16 row-major.
template <int BM, bool F16OUT, bool VOUT>
__global__ __launch_bounds__(256) void gemm_f16_kernel(const ushort* __restrict__ A,
                                                       const ushort* __restrict__ B,
                                                       void* __restrict__ Cout,
                                                       ushort* __restrict__ Vt,
                                                       int Nn) {
  constexpr int WM = BM / 2;   // 64 or 32
  constexpr int MR = WM / 16;  // 4 or 2
  constexpr int NR = 3;        // 48/16
  __shared__ __align__(16) ushort Asm[BM * 64];
  __shared__ __align__(16) ushort Bsm[96 * 64];
  const int tid = threadIdx.x;
  const int lane = tid & 63, w = tid >> 6;
  const int l15 = lane & 15, lg = lane >> 4;
  const int wr = w >> 1, wc = w & 1;
  const int m0 = blockIdx.y * BM, n0 = blockIdx.x * 96;
  const int srow = lane >> 3, lc = lane & 7;
  const int scp = lc ^ (srow & 7);  // pre-swizzled logical chunk

  f32x4 acc[MR][NR];
#pragma unroll
  for (int m = 0; m < MR; m++)
#pragma unroll
    for (int n = 0; n < NR; n++) acc[m][n] = (f32x4){0.f, 0.f, 0.f, 0.f};

  for (int k0 = 0; k0 < 768; k0 += 64) {
#pragma unroll
    for (int it = 0; it < BM / 32; it++) {
      int r0 = it * 32 + w * 8;
      int row = r0 + srow;
      gload_lds16(A + (size_t)(m0 + row) * CC + k0 + scp * 8, &Asm[r0 * 64]);
    }
#pragma unroll
    for (int it = 0; it < 3; it++) {
      int r0 = it * 32 + w * 8;
      int row = r0 + srow;
      gload_lds16(B + (size_t)(n0 + row) * CC + k0 + scp * 8, &Bsm[r0 * 64]);
    }
    __syncthreads();

    half8 ah[MR][2], bh[NR][2];
#pragma unroll
    for (int m = 0; m < MR; m++) {
      int row = wr * WM + m * 16 + l15;
#pragma unroll
      for (int s = 0; s < 2; s++)
        ah[m][s] = ld_h8(&Asm[row * 64 + ((s * 4 + lg) ^ (row & 7)) * 8]);
    }
#pragma unroll
    for (int n = 0; n < NR; n++) {
      int col = wc * 48 + n * 16 + l15;
#pragma unroll
      for (int s = 0; s < 2; s++)
        bh[n][s] = ld_h8(&Bsm[col * 64 + ((s * 4 + lg) ^ (col & 7)) * 8]);
    }
#pragma unroll
    for (int s = 0; s < 2; s++)
#pragma unroll
      for (int m = 0; m < MR; m++)
#pragma unroll
        for (int n = 0; n < NR; n++)
          acc[m][n] = MFMAH(ah[m][s], bh[n][s], acc[m][n]);
    __syncthreads();
  }

#pragma unroll
  for (int m = 0; m < MR; m++) {
    const int rbase = m0 + wr * WM + m * 16 + lg * 4;  // 4 consecutive tokens
#pragma unroll
    for (int n = 0; n < NR; n++) {
      int col = n0 + wc * 48 + n * 16 + l15;
      if (VOUT && col >= 1536) {
        // transposed V write: Vt[(b*NHEAD+h)*64+d][n..n+3]
        const int vcol = col - 1536;
        const int b = rbase >> 11, ntok = rbase & 2047;
        const int bh_ = b * NHEAD + (vcol >> 6), d = vcol & 63;
        uint2v pw = {pk2h(acc[m][n][0], acc[m][n][1]),
                     pk2h(acc[m][n][2], acc[m][n][3])};
        *reinterpret_cast<uint2v*>(Vt + ((size_t)bh_ * HD + d) * NN + ntok) = pw;
      } else {
#pragma unroll
        for (int j = 0; j < 4; j++) {
          if constexpr (F16OUT) {
            ((ushort*)Cout)[(size_t)(rbase + j) * Nn + col] = f2h(acc[m][n][j]);
          } else {
            ((float*)Cout)[(size_t)(rbase + j) * Nn + col] = acc[m][n][j];
          }
        }
      }
    }
  }
}

// ---------------- RoPE (Q/K) from f16 qkv -> f16, Q pre-scaled ----------------
__global__ __launch_bounds__(256) void rope_f16_kernel(
    const ushort* __restrict__ qkvh, const float* __restrict__ cos_t,
    const float* __restrict__ sin_t, const float* __restrict__ cos_h,
    const float* __restrict__ sin_h, const float* __restrict__ cos_w,
    const float* __restrict__ sin_w, const int* __restrict__ t_idx,
    const int* __restrict__ h_idx, const int* __restrict__ w_idx,
    ushort* __restrict__ Qf, ushort* __restrict__ Kf) {
  const int tok = blockIdx.x;  // 0..B*N-1
  const int b = tok >> 11, n = tok & 2047;
  const int ti = t_idx[n], hi = h_idx[n], wi = w_idx[n];
  const ushort* base = qkvh + (size_t)tok * C3;
  const float QSC = 0.125f * 1.44269504088896f;

#pragma unroll
  for (int s = 0; s < 3; s++) {
    int j = threadIdx.x + s * 256;
    float c, sn, sign;
    int pj;
    if (j < 192) {
      int jj = j;
      c = cos_t[ti * 192 + jj];
      sn = sin_t[ti * 192 + jj];
      pj = (jj < 96) ? j + 96 : j - 96;
      sign = (jj < 96) ? -1.f : 1.f;
    } else if (j < 480) {
      int jj = j - 192;
      c = cos_h[hi * 288 + jj];
      sn = sin_h[hi * 288 + jj];
      pj = (jj < 144) ? j + 144 : j - 144;
      sign = (jj < 144) ? -1.f : 1.f;
    } else {
      int jj = j - 480;
      c = cos_w[wi * 288 + jj];
      sn = sin_w[wi * 288 + jj];
      pj = (jj < 144) ? j + 144 : j - 144;
      sign = (jj < 144) ? -1.f : 1.f;
    }
    float qv = h2f(base[j]), kv = h2f(base[768 + j]);
    float qp = h2f(base[pj]) * sign, kp = h2f(base[768 + pj]) * sign;
    float qr = fmaf(qv, c, qp * sn) * QSC;
    float kr = fmaf(kv, c, kp * sn);
    int h = j >> 6, d = j & 63;
    int bh = b * NHEAD + h;
    size_t o = ((size_t)bh * NN + n) * HD + d;
    Qf[o] = f2h(qr);
    Kf[o] = f2h(kr);
  }
}

// ---------------- f16 MFMA flash attention, QBLK=64, split-K=2, 6 blocks/CU ----
// Exact R19 config: 24KB LDS (K single + V double), PV via 16x16x16, 40 VGPR.
__global__ __launch_bounds__(256, 6) void attn_mfma_kernel(
    const ushort* __restrict__ Qf, const ushort* __restrict__ Kf,
    const ushort* __restrict__ Vt, float* __restrict__ PartO,
    float* __restrict__ Partml) {
  __shared__ __align__(16) ushort smemK[4096];     // 8KB
  __shared__ __align__(16) ushort smemV[2][4096];  // 16KB
  const int tid = threadIdx.x;
  const int lane = tid & 63, w = tid >> 6;
  const int l15 = lane & 15, lg = lane >> 4;
  const int qt = blockIdx.x;  // 0..31 (64 q-rows each)
  const int bh = blockIdx.y;  // 0..23
  const int sp = blockIdx.z;  // 0..1 (k-range split)
  const size_t kbase = (size_t)bh * NN * HD;  // Qf/Kf token-major
  const size_t vbase = (size_t)bh * HD * NN;  // Vt d-major

  half8 qf[2];
  {
    const int r = qt * 64 + w * 16 + l15;
#pragma unroll
    for (int s = 0; s < 2; s++)
      qf[s] = ld_h8(Qf + kbase + (size_t)r * HD + s * 32 + lg * 8);
  }

  const int srow = lane >> 3;        // staging row-within-group 0..7
  const int sc = (lane & 7) ^ srow;  // pre-swizzled logical chunk

#define STAGE_K(kt_)                                                           \
  {                                                                            \
    _Pragma("unroll") for (int it = 0; it < 2; it++) {                         \
      int r0 = it * 32 + w * 8;                                                \
      int r = r0 + srow;                                                       \
      gload_lds16(Kf + kbase + (size_t)((kt_)*64 + r) * 64 + sc * 8,           \
                  &smemK[r0 * 64]);                                            \
    }                                                                          \
  }
#define STAGE_V(kt_, vb_)                                                      \
  {                                                                            \
    _Pragma("unroll") for (int it = 0; it < 2; it++) {                         \
      int r0 = it * 32 + w * 8;                                                \
      int r = r0 + srow;                                                       \
      gload_lds16(Vt + vbase + (size_t)r * NN + (kt_)*64 + sc * 8,             \
                  &smemV[vb_][r0 * 64]);                                       \
    }                                                                          \
  }

  f32x4 o_acc[4];
#pragma unroll
  for (int g = 0; g < 4; g++) o_acc[g] = (f32x4){0.f, 0.f, 0.f, 0.f};
  float m_run = -INFINITY, l_run = 0.f;  // per-lane partials

  const int rmask7 = l15 & 7;
  const int kt0 = sp * (32 / NSP), ktend = kt0 + (32 / NSP);

  STAGE_V(kt0, 0);
  STAGE_K(kt0);

  for (int kt = kt0; kt < ktend; kt++) {
    const int cur = (kt - kt0) & 1;
    __syncthreads();  // barA: K(kt), V(kt,cur) visible; V[cur^1] free of reads
    if (kt + 1 < ktend) STAGE_V(kt + 1, cur ^ 1);  // lands under this tile

    // ---- S^T = K Q^T (f16, 16x16x32) ----
    f32x4 s_acc[4];
#pragma unroll
    for (int g = 0; g < 4; g++) s_acc[g] = (f32x4){0.f, 0.f, 0.f, 0.f};
    __builtin_amdgcn_s_setprio(1);
#pragma unroll
    for (int g = 0; g < 4; g++) {
      const int r = g * 16 + l15;
#pragma unroll
      for (int s = 0; s < 2; s++) {
        half8 ka = ld_h8(&smemK[r * 64 + ((s * 4 + lg) ^ rmask7) * 8]);
        s_acc[g] = MFMAH(ka, qf[s], s_acc[g]);
      }
    }
    __builtin_amdgcn_s_setprio(0);

    __syncthreads();                      // barB: all waves done reading K(kt)
    if (kt + 1 < ktend) STAGE_K(kt + 1);  // lands under softmax+PV

    // ---- softmax (exp2 domain), defer-max THR=8 ----
    float m0a = fmaxf(fmaxf(s_acc[0][0], s_acc[0][1]), fmaxf(s_acc[0][2], s_acc[0][3]));
    float m1a = fmaxf(fmaxf(s_acc[1][0], s_acc[1][1]), fmaxf(s_acc[1][2], s_acc[1][3]));
    float m2a = fmaxf(fmaxf(s_acc[2][0], s_acc[2][1]), fmaxf(s_acc[2][2], s_acc[2][3]));
    float m3a = fmaxf(fmaxf(s_acc[3][0], s_acc[3][1]), fmaxf(s_acc[3][2], s_acc[3][3]));
    float pm = fmaxf(fmaxf(m0a, m1a), fmaxf(m2a, m3a));
    pm = fmaxf(pm, __shfl_xor(pm, 16, 64));
    pm = fmaxf(pm, __shfl_xor(pm, 32, 64));
    if (!__all(pm - m_run <= 8.0f)) {
      const float mn = fmaxf(m_run, pm);
      const float corr = fast_exp2(m_run - mn);
      m_run = mn;
      l_run *= corr;
#pragma unroll
      for (int g = 0; g < 4; g++)
#pragma unroll
        for (int j = 0; j < 4; j++) o_acc[g][j] *= corr;
    }
    float p[4][4];
#pragma unroll
    for (int g = 0; g < 4; g++)
#pragma unroll
      for (int j = 0; j < 4; j++) {
        p[g][j] = fast_exp2(s_acc[g][j] - m_run);
        l_run += p[g][j];
      }

    // ---- PV via 16x16x16: B-frag = p[kb][0..3] directly (no butterfly) ----
    __builtin_amdgcn_s_setprio(1);
#pragma unroll
    for (int kb = 0; kb < 4; kb++) {
      uint2v pw = {pk2h(p[kb][0], p[kb][1]), pk2h(p[kb][2], p[kb][3])};
      half4 pbh = __builtin_bit_cast(half4, pw);
      const int c = kb * 2 + (lg >> 1);
      const int off = ((c ^ rmask7) * 8 + (lg & 1) * 4);
#pragma unroll
      for (int g = 0; g < 4; g++) {
        half4 va = ld_h4(&smemV[cur][(g * 16 + l15) * 64 + off]);
        o_acc[g] = MFMAH16(va, pbh, o_acc[g]);
      }
    }
    __builtin_amdgcn_s_setprio(0);
  }

  // ---- epilogue: reduce l across the 4 q-column lanes, write partials ----
  l_run += __shfl_xor(l_run, 16, 64);
  l_run += __shfl_xor(l_run, 32, 64);
  const int q = qt * 64 + w * 16 + l15;
  const size_t pidx = ((size_t)(sp * 24 + bh) * NN + q);
#pragma unroll
  for (int g = 0; g < 4; g++) {
    *reinterpret_cast<float4*>(&PartO[pidx * 64 + g * 16 + lg * 4]) =
        make_float4(o_acc[g][0], o_acc[g][1], o_acc[g][2], o_acc[g][3]);
  }
  if (lg == 0) {
    Partml[pidx * 2] = m_run;
    Partml[pidx * 2 + 1] = l_run;
  }
#undef STAGE_K
#undef STAGE_V
}

// ---------------- split-K combine: merge NSP partials -> attnf f16 ----------------
__global__ __launch_bounds__(256) void attn_combine_kernel(
    const float* __restrict__ PartO, const float* __restrict__ Partml,
    ushort* __restrict__ Attnf) {
  const int qt = blockIdx.x;  // 0..31
  const int bh = blockIdx.y;  // 0..23
  const int b = bh / NHEAD, h = bh % NHEAD;
  const int tid = threadIdx.x;
  const int q = qt * 64 + (tid >> 2);
  const int d0 = (tid & 3) * 16;

  size_t idx[NSP];
  float mv[NSP], lv[NSP];
  float m = -INFINITY;
#pragma unroll
  for (int s = 0; s < NSP; s++) {
    idx[s] = ((size_t)(s * 24 + bh) * NN + q);
    mv[s] = Partml[idx[s] * 2];
    lv[s] = Partml[idx[s] * 2 + 1];
    m = fmaxf(m, mv[s]);
  }
  float wsum = 0.f, wgt[NSP];
#pragma unroll
  for (int s = 0; s < NSP; s++) {
    wgt[s] = fast_exp2(mv[s] - m);
    wsum += lv[s] * wgt[s];
  }
  const float inv = 1.0f / wsum;

  ushort hv[16];
#pragma unroll
  for (int d = 0; d < 16; d += 4) {
    float acc[4] = {0.f, 0.f, 0.f, 0.f};
#pragma unroll
    for (int s = 0; s < NSP; s++) {
      float4 a = *reinterpret_cast<const float4*>(&PartO[idx[s] * 64 + d0 + d]);
      acc[0] = fmaf(a.x, wgt[s], acc[0]);
      acc[1] = fmaf(a.y, wgt[s], acc[1]);
      acc[2] = fmaf(a.z, wgt[s], acc[2]);
      acc[3] = fmaf(a.w, wgt[s], acc[3]);
    }
#pragma unroll
    for (int i = 0; i < 4; i++) hv[d + i] = f2h(acc[i] * inv);
  }
  ushort* dst = Attnf + (size_t)(b * NN + q) * CC + h * 64 + d0;
  *reinterpret_cast<uint4*>(dst) = *reinterpret_cast<uint4*>(hv);
  *reinterpret_cast<uint4*>(dst + 8) = *reinterpret_cast<uint4*>(hv + 8);
}

// ---------------- launch ----------------
extern "C" void kernel_launch(void* const* d_in, const int* in_sizes, int n_in,
                              void* d_out, int out_size, void* d_ws, size_t ws_size,
                              hipStream_t stream) {
  const float* x = (const float*)d_in[0];
  const float* Wqkv = (const float*)d_in[1];
  const float* Wout = (const float*)d_in[2];
  const float* cos_t = (const float*)d_in[3];
  const float* sin_t = (const float*)d_in[4];
  const float* cos_h = (const float*)d_in[5];
  const float* sin_h = (const float*)d_in[6];
  const float* cos_w = (const float*)d_in[7];
  const float* sin_w = (const float*)d_in[8];
  const int* t_idx = (const int*)d_in[9];
  const int* h_idx = (const int*)d_in[10];
  const int* w_idx = (const int*)d_in[11];
  float* out = (float*)d_out;

  // region0: aliased by qkvh (f16 4096x2304, live gemm->rope) and
  // PartO (NSP*24*2048*64 f32 = 6.29M floats, live attn->combine). Disjoint.
  const size_t R0 = (size_t)4096 * 2304;  // floats
  float* ws = (float*)d_ws;
  ushort* qkvh = (ushort*)ws;
  float* PartO = ws;
  ushort* us = (ushort*)(ws + R0);
  const size_t HS = (size_t)24 * 2048 * 64;  // 3.14M
  ushort* Qf = us;
  ushort* Kf = Qf + HS;
  ushort* Vt = Kf + HS;
  ushort* xf = Vt + HS;                     // 4096*768
  ushort* wqf = xf + (size_t)4096 * 768;    // 2304*768
  ushort* wof = wqf + (size_t)2304 * 768;   // 768*768
  ushort* attnf = wof + (size_t)768 * 768;  // 4096*768
  float* Partml = (float*)(attnf + (size_t)4096 * 768);  // NSP*24*2048*2 fp32

  // input conversions (f16)
  conv_rows_kernel<<<dim3(4096 * 768 / 8 / 256), 256, 0, stream>>>(x, xf);
  conv_transpose_kernel<<<dim3(C3 / 32, CC / 32), 256, 0, stream>>>(Wqkv, wqf, C3);
  conv_transpose_kernel<<<dim3(CC / 32, CC / 32), 256, 0, stream>>>(Wout, wof, CC);
  // qkv = x @ Wqkv; q,k -> qkvh f16 row-major, v -> Vt transposed directly
  gemm_f16_kernel<128, true, true><<<dim3(C3 / 96, 4096 / 128), 256, 0, stream>>>(
      xf, wqf, qkvh, Vt, C3);
  // RoPE Q/K (f16 in/out)
  rope_f16_kernel<<<dim3(BB * NN), 256, 0, stream>>>(qkvh, cos_t, sin_t, cos_h, sin_h,
                                                     cos_w, sin_w, t_idx, h_idx, w_idx,
                                                     Qf, Kf);
  // flash attention (f16 MFMA, QBLK=64, split-K=2 -> 1536 blocks = 6/CU)
  attn_mfma_kernel<<<dim3(NN / 64, BB * NHEAD, NSP), 256, 0, stream>>>(Qf, Kf, Vt,
                                                                       PartO, Partml);
  // combine partials -> f16 attnf
  attn_combine_kernel<<<dim3(NN / 64, BB * NHEAD), 256, 0, stream>>>(PartO, Partml,
                                                                     attnf);
  // out = attn @ Wout  (f16 MFMA, fp32 output)
  gemm_f16_kernel<64, false, false><<<dim3(CC / 96, 4096 / 64), 256, 0, stream>>>(
      attnf, wof, out, nullptr, CC);
}